// Round 11
// baseline (495.395 us; speedup 1.0000x reference)
//
#include <hip/hip_runtime.h>
#include <stdint.h>

#define T_TOK 4096
#define DIMD  1024
#define HIDN  2048
#define NEXP  8
#define RMAX  10240                 // routed: 8192 slots + 8*256 alignment pad
#define RROWS (RMAX + 2 * T_TOK)    // 18432 = 72*256 = 144*128 rows total

typedef float f32x4 __attribute__((ext_vector_type(4)));
typedef short s16x8 __attribute__((ext_vector_type(8)));

__device__ __forceinline__ uint16_t f2bf(float f) {
    uint32_t u = __builtin_bit_cast(uint32_t, f);
    u += 0x7fffu + ((u >> 16) & 1u);
    return (uint16_t)(u >> 16);
}
__device__ __forceinline__ float bf2f(uint32_t h) {
    return __builtin_bit_cast(float, h << 16);
}
__device__ __forceinline__ uint32_t pk2(float a, float b) {
    return (uint32_t)f2bf(a) | ((uint32_t)f2bf(b) << 16);
}
__device__ __forceinline__ void gload16(const void* g, void* l) {
    __builtin_amdgcn_global_load_lds(
        (const __attribute__((address_space(1))) void*)g,
        (__attribute__((address_space(3))) void*)l, 16, 0, 0);
}
#define BAR()        asm volatile("s_barrier" ::: "memory")
#define WAIT_VM8()   asm volatile("s_waitcnt vmcnt(8)" ::: "memory")
#define WAIT_VM4()   asm volatile("s_waitcnt vmcnt(4)" ::: "memory")
#define WAIT_VM0()   asm volatile("s_waitcnt vmcnt(0)" ::: "memory")
#define WAIT_LGKM0() asm volatile("s_waitcnt lgkmcnt(0)" ::: "memory")

// ---------------- small kernels ----------------

struct CvtArgs {
    const float* s[7];
    uint16_t*    d[7];
    int          nq[7];
    int          mode[7];   // 0 straight, 1 w1->interleaved, 2 w3->interleaved
};

// w13 interleave: dest N-row n' = (n>>4)*32 + (mode==2?16:0) + (n&15): within each
// 32-row granule rows 0-15 are w1, 16-31 are w3 of the same 16 hidden channels.
__global__ void cvt_all_kernel(CvtArgs a) {
    int base = blockIdx.x * blockDim.x + threadIdx.x;
    int stride = gridDim.x * blockDim.x;
    #pragma unroll
    for (int seg = 0; seg < 7; ++seg) {
        const float4* sp = (const float4*)a.s[seg];
        uint2* dp = (uint2*)a.d[seg];
        int n = a.nq[seg];
        int mode = a.mode[seg];
        for (int i = base; i < n; i += stride) {
            float4 v = sp[i];
            uint2 o; o.x = pk2(v.x, v.y); o.y = pk2(v.z, v.w);
            int di = i;
            if (mode) {
                int e = i >> 19;            // quads per src expert: 2048*256 = 2^19
                int rem = i & 524287;
                int nr = rem >> 8;          // source N row
                int kq = rem & 255;
                int np = ((nr >> 4) << 5) + ((mode == 2) ? 16 : 0) + (nr & 15);
                di = (e << 20) + (np << 8) + kq;
            }
            dp[di] = o;
        }
    }
}

// Router: 128 blocks x 256 thr; rw staged in LDS; 1 wave = 8 tokens.
__global__ __launch_bounds__(256)
void router_kernel(const float* __restrict__ x, const float* __restrict__ rw,
                   const float* __restrict__ bias,
                   int* __restrict__ sel, float* __restrict__ wgt,
                   int* __restrict__ cnt) {
    __shared__ float rws[NEXP * DIMD];
    int tid = threadIdx.x;
    for (int i = tid; i < NEXP * DIMD / 4; i += 256)
        ((float4*)rws)[i] = ((const float4*)rw)[i];
    __syncthreads();

    int wid = tid >> 6, lane = tid & 63;
    float b[NEXP];
    #pragma unroll
    for (int e = 0; e < NEXP; ++e) b[e] = bias[e];

    int t0 = (blockIdx.x * 4 + wid) * 8;
    for (int j = 0; j < 8; ++j) {
        int t = t0 + j;
        const float4* xr = (const float4*)(x + (size_t)t * DIMD);
        float p[NEXP] = {};
        #pragma unroll
        for (int c = 0; c < 4; ++c) {
            float4 xv = xr[c * 64 + lane];
            #pragma unroll
            for (int e = 0; e < NEXP; ++e) {
                float4 wv = *(const float4*)(rws + e * DIMD + c * 256 + lane * 4);
                p[e] += xv.x * wv.x + xv.y * wv.y + xv.z * wv.z + xv.w * wv.w;
            }
        }
        #pragma unroll
        for (int off = 32; off >= 1; off >>= 1) {
            #pragma unroll
            for (int e = 0; e < NEXP; ++e) p[e] += __shfl_xor(p[e], off, 64);
        }
        if (lane == 0) {
            #pragma unroll
            for (int e = 0; e < NEXP; ++e) p[e] += b[e];
            float l0 = -1e30f; int i0 = 0;
            #pragma unroll
            for (int e = 0; e < NEXP; ++e) { if (p[e] > l0) { l0 = p[e]; i0 = e; } }
            float l1 = -1e30f; int i1 = 0;
            #pragma unroll
            for (int e = 0; e < NEXP; ++e) { if (e == i0) continue; if (p[e] > l1) { l1 = p[e]; i1 = e; } }
            float e1 = expf(l1 - l0);      // l0 >= l1 -> e1 <= 1
            float d = 1.f + e1;
            sel[t * 2] = i0; sel[t * 2 + 1] = i1;
            wgt[t * 2] = 1.f / d; wgt[t * 2 + 1] = e1 / d;
            atomicAdd(&cnt[i0], 1);
            atomicAdd(&cnt[i1], 1);
        }
    }
}

__global__ void offs_kernel(const int* __restrict__ cnt, int* __restrict__ offs) {
    if (threadIdx.x == 0 && blockIdx.x == 0) {
        int o = 0;
        for (int e = 0; e < NEXP; ++e) { offs[e] = o; o += (cnt[e] + 255) & ~255; }  // 256-align
        offs[NEXP] = o;
    }
}

__global__ void assign_kernel(const int* __restrict__ sel, const int* __restrict__ offs,
                              int* __restrict__ fill, int* __restrict__ row_of,
                              int* __restrict__ tok) {
    int i = blockIdx.x * blockDim.x + threadIdx.x;
    if (i < 2 * T_TOK) {
        int e = sel[i];
        int r = offs[e] + atomicAdd(&fill[e], 1);
        row_of[i] = r;
        tok[r] = i >> 1;
    } else if (i < 4 * T_TOK) {
        int j = i - 2 * T_TOK;                       // 0..8191: shared rows
        tok[offs[NEXP] + j] = j & (T_TOK - 1);
    }
}

// out[t] = w0*H2[r0] + w1*H2[r1] + H2[s0] + H2[s1]  (pure write)
__global__ void combine_kernel(const uint16_t* __restrict__ H2, const int* __restrict__ row_of,
                               const float* __restrict__ wgt, const int* __restrict__ offs,
                               float* __restrict__ out) {
    int t = blockIdx.x;
    int c = threadIdx.x * 8;   // 128 threads * 8 cols
    int r0 = row_of[t * 2], r1 = row_of[t * 2 + 1];
    int s0 = offs[NEXP] + t, s1 = s0 + T_TOK;
    float w0 = wgt[t * 2], w1 = wgt[t * 2 + 1];
    uint4 a = *(const uint4*)(H2 + (size_t)r0 * DIMD + c);
    uint4 b = *(const uint4*)(H2 + (size_t)r1 * DIMD + c);
    uint4 u = *(const uint4*)(H2 + (size_t)s0 * DIMD + c);
    uint4 v = *(const uint4*)(H2 + (size_t)s1 * DIMD + c);
    float4 o0, o1;
    o0.x = w0 * bf2f(a.x & 0xffffu) + w1 * bf2f(b.x & 0xffffu) + bf2f(u.x & 0xffffu) + bf2f(v.x & 0xffffu);
    o0.y = w0 * bf2f(a.x >> 16)     + w1 * bf2f(b.x >> 16)     + bf2f(u.x >> 16)     + bf2f(v.x >> 16);
    o0.z = w0 * bf2f(a.y & 0xffffu) + w1 * bf2f(b.y & 0xffffu) + bf2f(u.y & 0xffffu) + bf2f(v.y & 0xffffu);
    o0.w = w0 * bf2f(a.y >> 16)     + w1 * bf2f(b.y >> 16)     + bf2f(u.y >> 16)     + bf2f(v.y >> 16);
    o1.x = w0 * bf2f(a.z & 0xffffu) + w1 * bf2f(b.z & 0xffffu) + bf2f(u.z & 0xffffu) + bf2f(v.z & 0xffffu);
    o1.y = w0 * bf2f(a.z >> 16)     + w1 * bf2f(b.z >> 16)     + bf2f(u.z >> 16)     + bf2f(v.z >> 16);
    o1.z = w0 * bf2f(a.w & 0xffffu) + w1 * bf2f(b.w & 0xffffu) + bf2f(u.w & 0xffffu) + bf2f(v.w & 0xffffu);
    o1.w = w0 * bf2f(a.w >> 16)     + w1 * bf2f(b.w >> 16)     + bf2f(u.w >> 16)     + bf2f(v.w >> 16);
    float* o = out + (size_t)t * DIMD + c;
    *(float4*)o = o0;
    *(float4*)(o + 4) = o1;
}

// ------------- gemm13: 256x256, ring-4 ks-units, depth-3 counted-vmcnt -------------
// 512 thr = 8 waves (2M x 4N); per-wave C = 128x64 = acc[8][4] frags.
// Unit = K=32 slice; ring of 4 slots x 32KB {A 16K, B 16K} = 128KB.
// During unit u (2 phases) stage unit u+3 (A in ph1, B in ph2) -> prefetch
// distance 3 units (~6 phases ~900+ cyc) covers HBM latency (m126).
// Ledger: invariant at unit u entry = u landed, u+1/u+2 (8 loads) in flight;
// per-unit end-wait vmcnt(8) -> u+1 landed. Tail: u==NU-3 -> vm(4), NU-2 -> vm(0).
// Slot safety: stage(u+3) targets slot (u-1)&3, whose reads finished (lgkm0)
// before u-1's final barrier. Swizzle identical to r9 (0 conflicts measured).
__global__ __launch_bounds__(512, 2)
void gemm13_8p(const uint16_t* __restrict__ A, const int* __restrict__ tok,
               const uint16_t* __restrict__ W, uint16_t* __restrict__ H,
               const int* __restrict__ offs) {
    constexpr int K = DIMD;       // 1024
    constexpr int NU = K / 32;    // 32 ks-units
    __shared__ __align__(16) char lds[131072];

    int row0 = blockIdx.y * 256;
    int rsh = row0 - offs[NEXP];
    int e;
    if (rsh >= 0) {
        if (rsh >= 2 * T_TOK) return;
        e = NEXP + (rsh >> 12);
    } else {
        e = 0;
        while (row0 >= offs[e + 1]) ++e;
    }
    const uint16_t* wp = W + (size_t)e * (4096ull * 1024ull);
    int col0 = blockIdx.x * 256;

    int tid = threadIdx.x, lane = tid & 63, wid = tid >> 6;
    int wm = wid >> 2, wn = wid & 3;

    int sslot = (lane & 3) ^ ((tid >> 3) & 3);
    uint32_t aoff[2], boff[2];
    #pragma unroll
    for (int i = 0; i < 2; ++i) {
        int r = i * 128 + (tid >> 2);
        int garow = tok[row0 + r];
        aoff[i] = (uint32_t)garow * K + sslot * 8;
        boff[i] = (uint32_t)(col0 + r) * K + sslot * 8;
    }
    int ldsw = wid * 1024;

    int rslot = (((lane >> 4) ^ ((lane >> 1) & 3)) << 4);
    int aro = (wm * 128 + (lane & 15)) * 64 + rslot;   // + f*1024 within 16K A block
    int bro = (wn * 64 + (lane & 15)) * 64 + rslot;    // + f*1024 within 16K B block

    #define STAGE_A(buf, ku) { \
        gload16(A + aoff[0] + (ku), (buf) + ldsw); \
        gload16(A + aoff[1] + (ku), (buf) + 8192 + ldsw); }
    #define STAGE_B(buf, ku) { \
        gload16(wp + boff[0] + (ku), (buf) + 16384 + ldsw); \
        gload16(wp + boff[1] + (ku), (buf) + 16384 + 8192 + ldsw); }

    // prologue: stage units 0,1,2 (12 loads); wait for unit 0 (8 still flying)
    STAGE_A(lds, 0);                 STAGE_B(lds, 0);
    STAGE_A(lds + 32768, 32);        STAGE_B(lds + 32768, 32);
    STAGE_A(lds + 2 * 32768, 64);    STAGE_B(lds + 2 * 32768, 64);
    WAIT_VM8();
    BAR();

    f32x4 acc[8][4] = {};

    for (int u = 0; u < NU; ++u) {
        char* cur = lds + (u & 3) * 32768;
        char* nb  = lds + ((u + 3) & 3) * 32768;
        int ku = (u + 3) * 32;
        bool pre = (u + 3 < NU);
        s16x8 av[4], bv[4], av2[4];

        // ---- ph1: A frag-rows 0-3 + all B frags (8 ds_read) ; stage A(u+3)
        #pragma unroll
        for (int f = 0; f < 4; ++f) av[f] = *(const s16x8*)(cur + aro + f * 1024);
        #pragma unroll
        for (int f = 0; f < 4; ++f) bv[f] = *(const s16x8*)(cur + 16384 + bro + f * 1024);
        if (pre) STAGE_A(nb, ku);
        BAR(); WAIT_LGKM0();
        __builtin_amdgcn_s_setprio(1);
        #pragma unroll
        for (int j = 0; j < 4; ++j)
            #pragma unroll
            for (int i = 0; i < 4; ++i)
                acc[i][j] = __builtin_amdgcn_mfma_f32_16x16x32_bf16(av[i], bv[j], acc[i][j], 0, 0, 0);
        __builtin_amdgcn_s_setprio(0);
        BAR();

        // ---- ph2: A frag-rows 4-7 (4 ds_read) ; stage B(u+3)
        #pragma unroll
        for (int f = 0; f < 4; ++f) av2[f] = *(const s16x8*)(cur + aro + (f + 4) * 1024);
        if (pre) STAGE_B(nb, ku);
        BAR(); WAIT_LGKM0();
        __builtin_amdgcn_s_setprio(1);
        #pragma unroll
        for (int j = 0; j < 4; ++j)
            #pragma unroll
            for (int i = 0; i < 4; ++i)
                acc[i + 4][j] = __builtin_amdgcn_mfma_f32_16x16x32_bf16(av2[i], bv[j], acc[i + 4][j], 0, 0, 0);
        __builtin_amdgcn_s_setprio(0);
        if (u <= NU - 4)      { WAIT_VM8(); }   // u+1 landed; u+2,u+3 flying
        else if (u == NU - 3) { WAIT_VM4(); }   // only u+2 flying afterwards
        else if (u == NU - 2) { WAIT_VM0(); }   // drain last unit
        BAR();
    }
    #undef STAGE_A
    #undef STAGE_B

    // ---- epilogue: silu(w1-frag)*w3-frag; cols interleaved at 16 granule
    #pragma unroll
    for (int i = 0; i < 8; ++i) {
        int row = row0 + wm * 128 + i * 16 + ((lane >> 4) << 2);
        #pragma unroll
        for (int m = 0; m < 2; ++m) {
            int hc = ((col0 + wn * 64) >> 1) + m * 16 + (lane & 15);
            #pragma unroll
            for (int rg = 0; rg < 4; ++rg) {
                float a1 = acc[i][2 * m][rg];
                float a3 = acc[i][2 * m + 1][rg];
                float hv = (a1 / (1.f + __expf(-a1))) * a3;
                H[(size_t)(row + rg) * HIDN + hc] = f2bf(hv);
            }
        }
    }
}

// ------------- gemm2: 128x128, ring-4 ks-units, depth-3 counted-vmcnt -------------
// 256 thr = 4 waves (2x2). Unit = K=32; ring 4 slots x 16KB {A 8K, B 8K} = 64KB
// -> 2 blocks/CU. One phase per unit: {8 ds_read ∥ stage unit u+3 (4 loads),
// BAR, lgkm0, setprio, 16 MFMA, setprio0, vmcnt(8), BAR}. Same ledger as gemm13.
__global__ __launch_bounds__(256, 2)
void gemm2_2p(const uint16_t* __restrict__ Hg,
              const uint16_t* __restrict__ W2, uint16_t* __restrict__ H2,
              const int* __restrict__ offs) {
    constexpr int K = HIDN;       // 2048
    constexpr int NU = K / 32;    // 64 ks-units
    __shared__ __align__(16) char lds[65536];

    int row0 = blockIdx.y * 128;
    int rsh = row0 - offs[NEXP];
    int e;
    if (rsh >= 0) {
        if (rsh >= 2 * T_TOK) return;
        e = NEXP + (rsh >> 12);
    } else {
        e = 0;
        while (row0 >= offs[e + 1]) ++e;
    }
    const uint16_t* wp = W2 + (size_t)e * DIMD * HIDN;
    int col0 = blockIdx.x * 128;

    int tid = threadIdx.x, lane = tid & 63, wid = tid >> 6;
    int wm = wid >> 1, wn = wid & 1;

    int chunk = (tid & 3) ^ ((tid >> 3) & 3);
    uint32_t aoff[2], boff[2];
    #pragma unroll
    for (int p = 0; p < 2; ++p) {
        int r = p * 64 + (tid >> 2);
        aoff[p] = (uint32_t)(row0 + r) * K + chunk * 8;
        boff[p] = (uint32_t)(col0 + r) * K + chunk * 8;
    }
    int ldsw = wid * 1024;

    int rslot = (((lane >> 4) ^ ((lane >> 1) & 3)) << 4);
    int aro = (wm * 64 + (lane & 15)) * 64 + rslot;    // + f*1024 within 8K A block
    int bro = (wn * 64 + (lane & 15)) * 64 + rslot;    // + f*1024 within 8K B block

    #define STG_A2(buf, ku) { \
        gload16(Hg + aoff[0] + (ku), (buf) + ldsw); \
        gload16(Hg + aoff[1] + (ku), (buf) + 4096 + ldsw); }
    #define STG_B2(buf, ku) { \
        gload16(wp + boff[0] + (ku), (buf) + 8192 + ldsw); \
        gload16(wp + boff[1] + (ku), (buf) + 8192 + 4096 + ldsw); }

    // prologue: stage units 0,1,2 (12 loads); wait unit 0 (8 flying)
    STG_A2(lds, 0);                STG_B2(lds, 0);
    STG_A2(lds + 16384, 32);       STG_B2(lds + 16384, 32);
    STG_A2(lds + 2 * 16384, 64);   STG_B2(lds + 2 * 16384, 64);
    WAIT_VM8();
    BAR();

    f32x4 acc[4][4] = {};

    for (int u = 0; u < NU; ++u) {
        char* cur = lds + (u & 3) * 16384;
        char* nb  = lds + ((u + 3) & 3) * 16384;
        int ku = (u + 3) * 32;
        bool pre = (u + 3 < NU);
        s16x8 av[4], bv[4];

        #pragma unroll
        for (int f = 0; f < 4; ++f) av[f] = *(const s16x8*)(cur + aro + f * 1024);
        #pragma unroll
        for (int f = 0; f < 4; ++f) bv[f] = *(const s16x8*)(cur + 8192 + bro + f * 1024);
        if (pre) { STG_A2(nb, ku); STG_B2(nb, ku); }
        BAR(); WAIT_LGKM0();
        __builtin_amdgcn_s_setprio(1);
        #pragma unroll
        for (int j = 0; j < 4; ++j)
            #pragma unroll
            for (int i = 0; i < 4; ++i)
                acc[i][j] = __builtin_amdgcn_mfma_f32_16x16x32_bf16(av[i], bv[j], acc[i][j], 0, 0, 0);
        __builtin_amdgcn_s_setprio(0);
        if (u <= NU - 4)      { WAIT_VM8(); }
        else if (u == NU - 3) { WAIT_VM4(); }
        else if (u == NU - 2) { WAIT_VM0(); }
        BAR();
    }
    #undef STG_A2
    #undef STG_B2

    #pragma unroll
    for (int i = 0; i < 4; ++i) {
        #pragma unroll
        for (int j = 0; j < 4; ++j) {
            #pragma unroll
            for (int rg = 0; rg < 4; ++rg) {
                int row = row0 + wm * 64 + i * 16 + ((lane >> 4) << 2) + rg;
                int col = col0 + wn * 64 + j * 16 + (lane & 15);
                H2[(size_t)row * DIMD + col] = f2bf(acc[i][j][rg]);
            }
        }
    }
}

// ---------------- launch ----------------

extern "C" void kernel_launch(void* const* d_in, const int* in_sizes, int n_in,
                              void* d_out, int out_size, void* d_ws, size_t ws_size,
                              hipStream_t stream) {
    const float* x   = (const float*)d_in[0];
    const float* rw  = (const float*)d_in[1];
    const float* eb  = (const float*)d_in[2];
    const float* w1  = (const float*)d_in[3];
    const float* w3  = (const float*)d_in[4];
    const float* w2  = (const float*)d_in[5];
    const float* sw1 = (const float*)d_in[6];
    const float* sw3 = (const float*)d_in[7];
    const float* sw2 = (const float*)d_in[8];
    float* out = (float*)d_out;

    const size_t EW = (size_t)NEXP * HIDN * DIMD;
    const size_t SW = (size_t)2 * HIDN * DIMD;

    char* ws = (char*)d_ws;
    size_t off = 0;
    auto alloc = [&](size_t b) { char* p = ws + off; off = (off + b + 255) & ~(size_t)255; return p; };
    uint16_t* xb    = (uint16_t*)alloc((size_t)T_TOK * DIMD * 2);
    uint16_t* Hg    = (uint16_t*)alloc((size_t)RROWS * HIDN * 2);
    uint16_t* H2    = (uint16_t*)alloc((size_t)RROWS * DIMD * 2);
    uint16_t* w13   = (uint16_t*)alloc((size_t)10 * 4096 * 1024 * 2);  // interleaved, 10 experts
    uint16_t* w2all = (uint16_t*)alloc((EW + SW) * 2);
    int*   sel    = (int*)  alloc(T_TOK * 2 * 4);
    float* wgt    = (float*)alloc(T_TOK * 2 * 4);
    int*   row_of = (int*)  alloc(T_TOK * 2 * 4);
    int*   tok    = (int*)  alloc(RROWS * 4);
    int*   cnt    = (int*)  alloc(64);
    int*   fill   = (int*)  alloc(64);
    int*   offs   = (int*)  alloc(64);

    hipMemsetAsync(cnt, 0, 64, stream);
    hipMemsetAsync(fill, 0, 64, stream);
    hipMemsetAsync(tok, 0, RROWS * 4, stream);   // pad rows -> token 0 (harmless)

    CvtArgs ca;
    ca.s[0] = w1;  ca.d[0] = w13;                           ca.nq[0] = (int)(EW / 4); ca.mode[0] = 1;
    ca.s[1] = sw1; ca.d[1] = w13 + (size_t)8 * 4096 * 1024; ca.nq[1] = (int)(SW / 4); ca.mode[1] = 1;
    ca.s[2] = w3;  ca.d[2] = w13;                           ca.nq[2] = (int)(EW / 4); ca.mode[2] = 2;
    ca.s[3] = sw3; ca.d[3] = w13 + (size_t)8 * 4096 * 1024; ca.nq[3] = (int)(SW / 4); ca.mode[3] = 2;
    ca.s[4] = w2;  ca.d[4] = w2all;                         ca.nq[4] = (int)(EW / 4); ca.mode[4] = 0;
    ca.s[5] = sw2; ca.d[5] = w2all + EW;                    ca.nq[5] = (int)(SW / 4); ca.mode[5] = 0;
    ca.s[6] = x;   ca.d[6] = xb;                            ca.nq[6] = T_TOK * DIMD / 4; ca.mode[6] = 0;
    cvt_all_kernel<<<2048, 256, 0, stream>>>(ca);

    router_kernel<<<128, 256, 0, stream>>>(x, rw, eb, sel, wgt, cnt);
    offs_kernel<<<1, 1, 0, stream>>>(cnt, offs);
    assign_kernel<<<64, 256, 0, stream>>>(sel, offs, fill, row_of, tok);

    gemm13_8p<<<dim3(16, RROWS / 256), 512, 0, stream>>>(xb, tok, w13, Hg, offs);
    gemm2_2p<<<dim3(DIMD / 128, RROWS / 128), 256, 0, stream>>>(Hg, w2all, H2, offs);

    combine_kernel<<<T_TOK, 128, 0, stream>>>(H2, row_of, wgt, offs, out);
}

// Round 12
// 482.531 us; speedup vs baseline: 1.0267x; 1.0267x over previous
//
#include <hip/hip_runtime.h>
#include <stdint.h>

#define T_TOK 4096
#define DIMD  1024
#define HIDN  2048
#define NEXP  8
#define RMAX  10240                 // routed: 8192 slots + 8*256 alignment pad
#define RROWS (RMAX + 2 * T_TOK)    // 18432 = 72*256 = 144*128 rows total

typedef float f32x4 __attribute__((ext_vector_type(4)));
typedef short s16x8 __attribute__((ext_vector_type(8)));

__device__ __forceinline__ uint16_t f2bf(float f) {
    uint32_t u = __builtin_bit_cast(uint32_t, f);
    u += 0x7fffu + ((u >> 16) & 1u);
    return (uint16_t)(u >> 16);
}
__device__ __forceinline__ float bf2f(uint32_t h) {
    return __builtin_bit_cast(float, h << 16);
}
__device__ __forceinline__ uint32_t pk2(float a, float b) {
    return (uint32_t)f2bf(a) | ((uint32_t)f2bf(b) << 16);
}
__device__ __forceinline__ void gload16(const void* g, void* l) {
    __builtin_amdgcn_global_load_lds(
        (const __attribute__((address_space(1))) void*)g,
        (__attribute__((address_space(3))) void*)l, 16, 0, 0);
}
#define BAR()        asm volatile("s_barrier" ::: "memory")
#define WAIT_VM4()   asm volatile("s_waitcnt vmcnt(4)" ::: "memory")
#define WAIT_VM0()   asm volatile("s_waitcnt vmcnt(0)" ::: "memory")
#define WAIT_LGKM0() asm volatile("s_waitcnt lgkmcnt(0)" ::: "memory")

// ---------------- small kernels ----------------

struct CvtArgs {
    const float* s[7];
    uint16_t*    d[7];
    int          nq[7];
    int          mode[7];   // 0 straight, 1 w1->interleaved, 2 w3->interleaved
};

// w13 interleave: dest N-row n' = (n>>4)*32 + (mode==2?16:0) + (n&15): within each
// 32-row granule rows 0-15 are w1, 16-31 are w3 of the same 16 hidden channels.
__global__ void cvt_all_kernel(CvtArgs a) {
    int base = blockIdx.x * blockDim.x + threadIdx.x;
    int stride = gridDim.x * blockDim.x;
    #pragma unroll
    for (int seg = 0; seg < 7; ++seg) {
        const float4* sp = (const float4*)a.s[seg];
        uint2* dp = (uint2*)a.d[seg];
        int n = a.nq[seg];
        int mode = a.mode[seg];
        for (int i = base; i < n; i += stride) {
            float4 v = sp[i];
            uint2 o; o.x = pk2(v.x, v.y); o.y = pk2(v.z, v.w);
            int di = i;
            if (mode) {
                int e = i >> 19;            // quads per src expert: 2048*256 = 2^19
                int rem = i & 524287;
                int nr = rem >> 8;          // source N row
                int kq = rem & 255;
                int np = ((nr >> 4) << 5) + ((mode == 2) ? 16 : 0) + (nr & 15);
                di = (e << 20) + (np << 8) + kq;
            }
            dp[di] = o;
        }
    }
}

// Router: 128 blocks x 256 thr; rw staged in LDS; 1 wave = 8 tokens.
__global__ __launch_bounds__(256)
void router_kernel(const float* __restrict__ x, const float* __restrict__ rw,
                   const float* __restrict__ bias,
                   int* __restrict__ sel, float* __restrict__ wgt,
                   int* __restrict__ cnt) {
    __shared__ float rws[NEXP * DIMD];
    int tid = threadIdx.x;
    for (int i = tid; i < NEXP * DIMD / 4; i += 256)
        ((float4*)rws)[i] = ((const float4*)rw)[i];
    __syncthreads();

    int wid = tid >> 6, lane = tid & 63;
    float b[NEXP];
    #pragma unroll
    for (int e = 0; e < NEXP; ++e) b[e] = bias[e];

    int t0 = (blockIdx.x * 4 + wid) * 8;
    for (int j = 0; j < 8; ++j) {
        int t = t0 + j;
        const float4* xr = (const float4*)(x + (size_t)t * DIMD);
        float p[NEXP] = {};
        #pragma unroll
        for (int c = 0; c < 4; ++c) {
            float4 xv = xr[c * 64 + lane];
            #pragma unroll
            for (int e = 0; e < NEXP; ++e) {
                float4 wv = *(const float4*)(rws + e * DIMD + c * 256 + lane * 4);
                p[e] += xv.x * wv.x + xv.y * wv.y + xv.z * wv.z + xv.w * wv.w;
            }
        }
        #pragma unroll
        for (int off = 32; off >= 1; off >>= 1) {
            #pragma unroll
            for (int e = 0; e < NEXP; ++e) p[e] += __shfl_xor(p[e], off, 64);
        }
        if (lane == 0) {
            #pragma unroll
            for (int e = 0; e < NEXP; ++e) p[e] += b[e];
            float l0 = -1e30f; int i0 = 0;
            #pragma unroll
            for (int e = 0; e < NEXP; ++e) { if (p[e] > l0) { l0 = p[e]; i0 = e; } }
            float l1 = -1e30f; int i1 = 0;
            #pragma unroll
            for (int e = 0; e < NEXP; ++e) { if (e == i0) continue; if (p[e] > l1) { l1 = p[e]; i1 = e; } }
            float e1 = expf(l1 - l0);      // l0 >= l1 -> e1 <= 1
            float d = 1.f + e1;
            sel[t * 2] = i0; sel[t * 2 + 1] = i1;
            wgt[t * 2] = 1.f / d; wgt[t * 2 + 1] = e1 / d;
            atomicAdd(&cnt[i0], 1);
            atomicAdd(&cnt[i1], 1);
        }
    }
}

__global__ void offs_kernel(const int* __restrict__ cnt, int* __restrict__ offs) {
    if (threadIdx.x == 0 && blockIdx.x == 0) {
        int o = 0;
        for (int e = 0; e < NEXP; ++e) { offs[e] = o; o += (cnt[e] + 255) & ~255; }  // 256-align
        offs[NEXP] = o;
    }
}

__global__ void assign_kernel(const int* __restrict__ sel, const int* __restrict__ offs,
                              int* __restrict__ fill, int* __restrict__ row_of,
                              int* __restrict__ tok) {
    int i = blockIdx.x * blockDim.x + threadIdx.x;
    if (i < 2 * T_TOK) {
        int e = sel[i];
        int r = offs[e] + atomicAdd(&fill[e], 1);
        row_of[i] = r;
        tok[r] = i >> 1;
    } else if (i < 4 * T_TOK) {
        int j = i - 2 * T_TOK;                       // 0..8191: shared rows
        tok[offs[NEXP] + j] = j & (T_TOK - 1);
    }
}

// out[t] = w0*H2[r0] + w1*H2[r1] + H2[s0] + H2[s1]  (pure write)
__global__ void combine_kernel(const uint16_t* __restrict__ H2, const int* __restrict__ row_of,
                               const float* __restrict__ wgt, const int* __restrict__ offs,
                               float* __restrict__ out) {
    int t = blockIdx.x;
    int c = threadIdx.x * 8;   // 128 threads * 8 cols
    int r0 = row_of[t * 2], r1 = row_of[t * 2 + 1];
    int s0 = offs[NEXP] + t, s1 = s0 + T_TOK;
    float w0 = wgt[t * 2], w1 = wgt[t * 2 + 1];
    uint4 a = *(const uint4*)(H2 + (size_t)r0 * DIMD + c);
    uint4 b = *(const uint4*)(H2 + (size_t)r1 * DIMD + c);
    uint4 u = *(const uint4*)(H2 + (size_t)s0 * DIMD + c);
    uint4 v = *(const uint4*)(H2 + (size_t)s1 * DIMD + c);
    float4 o0, o1;
    o0.x = w0 * bf2f(a.x & 0xffffu) + w1 * bf2f(b.x & 0xffffu) + bf2f(u.x & 0xffffu) + bf2f(v.x & 0xffffu);
    o0.y = w0 * bf2f(a.x >> 16)     + w1 * bf2f(b.x >> 16)     + bf2f(u.x >> 16)     + bf2f(v.x >> 16);
    o0.z = w0 * bf2f(a.y & 0xffffu) + w1 * bf2f(b.y & 0xffffu) + bf2f(u.y & 0xffffu) + bf2f(v.y & 0xffffu);
    o0.w = w0 * bf2f(a.y >> 16)     + w1 * bf2f(b.y >> 16)     + bf2f(u.y >> 16)     + bf2f(v.y >> 16);
    o1.x = w0 * bf2f(a.z & 0xffffu) + w1 * bf2f(b.z & 0xffffu) + bf2f(u.z & 0xffffu) + bf2f(v.z & 0xffffu);
    o1.y = w0 * bf2f(a.z >> 16)     + w1 * bf2f(b.z >> 16)     + bf2f(u.z >> 16)     + bf2f(v.z >> 16);
    o1.z = w0 * bf2f(a.w & 0xffffu) + w1 * bf2f(b.w & 0xffffu) + bf2f(u.w & 0xffffu) + bf2f(v.w & 0xffffu);
    o1.w = w0 * bf2f(a.w >> 16)     + w1 * bf2f(b.w >> 16)     + bf2f(u.w >> 16)     + bf2f(v.w >> 16);
    float* o = out + (size_t)t * DIMD + c;
    *(float4*)o = o0;
    *(float4*)(o + 4) = o1;
}

// ------------- gemm13: 256x256 tile, BK=64, 4-phase counted-vmcnt (r9) + XCD swizzle -------------
// 1D grid 1152 = 16 col x 72 row; chunked-XCD map wgid=(orig%8)*144+orig/8 pins
// 144 contiguous tiles (9 row-panels x 16 cols) per XCD -> A-panel re-reads are L2 hits.
__global__ __launch_bounds__(512, 2)
void gemm13_8p(const uint16_t* __restrict__ A, const int* __restrict__ tok,
               const uint16_t* __restrict__ W, uint16_t* __restrict__ H,
               const int* __restrict__ offs) {
    constexpr int K = DIMD;       // 1024
    constexpr int NT = K / 64;    // 16 K-tiles
    __shared__ __align__(16) char lds[131072];

    int wg = ((blockIdx.x & 7) * 144) + (blockIdx.x >> 3);   // bijective, nwg%8==0
    int row0 = (wg >> 4) * 256;
    int col0 = (wg & 15) * 256;

    int rsh = row0 - offs[NEXP];
    int e;
    if (rsh >= 0) {
        if (rsh >= 2 * T_TOK) return;
        e = NEXP + (rsh >> 12);
    } else {
        e = 0;
        while (row0 >= offs[e + 1]) ++e;
    }
    const uint16_t* wp = W + (size_t)e * (4096ull * 1024ull);

    int tid = threadIdx.x, lane = tid & 63, wid = tid >> 6;
    int wm = wid >> 2, wn = wid & 3;

    int sslot = (lane & 3) ^ ((tid >> 3) & 3);
    uint32_t aoff[2], boff[2];
    #pragma unroll
    for (int i = 0; i < 2; ++i) {
        int r = i * 128 + (tid >> 2);
        int garow = tok[row0 + r];
        aoff[i] = (uint32_t)garow * K + sslot * 8;
        boff[i] = (uint32_t)(col0 + r) * K + sslot * 8;
    }
    int ldsw = wid * 1024;

    int rslot = (((lane >> 4) ^ ((lane >> 1) & 3)) << 4);
    int aro = (wm * 128 + (lane & 15)) * 64 + rslot;
    int bro = (wn * 64 + (lane & 15)) * 64 + rslot;

    #define STAGE_A(buf, kt, ks) { \
        gload16(A + aoff[0] + (kt) + (ks) * 32, (buf) + (ks) * 16384 + ldsw); \
        gload16(A + aoff[1] + (kt) + (ks) * 32, (buf) + (ks) * 16384 + 8192 + ldsw); }
    #define STAGE_B(buf, kt, ks) { \
        gload16(wp + boff[0] + (kt) + (ks) * 32, (buf) + 32768 + (ks) * 16384 + ldsw); \
        gload16(wp + boff[1] + (kt) + (ks) * 32, (buf) + 32768 + (ks) * 16384 + 8192 + ldsw); }

    STAGE_A(lds, 0, 0); STAGE_B(lds, 0, 0);
    STAGE_A(lds, 0, 1); STAGE_B(lds, 0, 1);
    WAIT_VM4();
    BAR();

    f32x4 acc[8][4] = {};

    for (int t = 0; t < NT; ++t) {
        char* cur = lds + (t & 1) * 65536;
        char* nxt = lds + ((t + 1) & 1) * 65536;
        int kt1 = (t + 1) * 64;
        bool pre = (t + 1 < NT);
        s16x8 av[4], bv[4], av2[4];

        // ---- ph1: ks0, frag-rows 0-3 ; stage Aks0(t+1)
        #pragma unroll
        for (int f = 0; f < 4; ++f) av[f] = *(const s16x8*)(cur + aro + f * 1024);
        #pragma unroll
        for (int f = 0; f < 4; ++f) bv[f] = *(const s16x8*)(cur + 32768 + bro + f * 1024);
        if (pre) STAGE_A(nxt, kt1, 0);
        BAR(); WAIT_LGKM0();
        __builtin_amdgcn_s_setprio(1);
        #pragma unroll
        for (int j = 0; j < 4; ++j)
            #pragma unroll
            for (int i = 0; i < 4; ++i)
                acc[i][j] = __builtin_amdgcn_mfma_f32_16x16x32_bf16(av[i], bv[j], acc[i][j], 0, 0, 0);
        __builtin_amdgcn_s_setprio(0);
        BAR();

        // ---- ph2: ks0, frag-rows 4-7 ; stage Bks0(t+1)
        #pragma unroll
        for (int f = 0; f < 4; ++f) av2[f] = *(const s16x8*)(cur + aro + (f + 4) * 1024);
        if (pre) STAGE_B(nxt, kt1, 0);
        BAR(); WAIT_LGKM0();
        __builtin_amdgcn_s_setprio(1);
        #pragma unroll
        for (int j = 0; j < 4; ++j)
            #pragma unroll
            for (int i = 0; i < 4; ++i)
                acc[i + 4][j] = __builtin_amdgcn_mfma_f32_16x16x32_bf16(av2[i], bv[j], acc[i + 4][j], 0, 0, 0);
        __builtin_amdgcn_s_setprio(0);
        if (pre) { WAIT_VM4(); } else { WAIT_VM0(); }
        BAR();

        // ---- ph3: ks1, frag-rows 0-3 ; stage Aks1(t+1)
        #pragma unroll
        for (int f = 0; f < 4; ++f) av[f] = *(const s16x8*)(cur + 16384 + aro + f * 1024);
        #pragma unroll
        for (int f = 0; f < 4; ++f) bv[f] = *(const s16x8*)(cur + 32768 + 16384 + bro + f * 1024);
        if (pre) STAGE_A(nxt, kt1, 1);
        BAR(); WAIT_LGKM0();
        __builtin_amdgcn_s_setprio(1);
        #pragma unroll
        for (int j = 0; j < 4; ++j)
            #pragma unroll
            for (int i = 0; i < 4; ++i)
                acc[i][j] = __builtin_amdgcn_mfma_f32_16x16x32_bf16(av[i], bv[j], acc[i][j], 0, 0, 0);
        __builtin_amdgcn_s_setprio(0);
        BAR();

        // ---- ph4: ks1, frag-rows 4-7 ; stage Bks1(t+1)
        #pragma unroll
        for (int f = 0; f < 4; ++f) av2[f] = *(const s16x8*)(cur + 16384 + aro + (f + 4) * 1024);
        if (pre) STAGE_B(nxt, kt1, 1);
        BAR(); WAIT_LGKM0();
        __builtin_amdgcn_s_setprio(1);
        #pragma unroll
        for (int j = 0; j < 4; ++j)
            #pragma unroll
            for (int i = 0; i < 4; ++i)
                acc[i + 4][j] = __builtin_amdgcn_mfma_f32_16x16x32_bf16(av2[i], bv[j], acc[i + 4][j], 0, 0, 0);
        __builtin_amdgcn_s_setprio(0);
        if (pre) WAIT_VM4();
        BAR();
    }
    #undef STAGE_A
    #undef STAGE_B

    // ---- epilogue: silu(w1-frag)*w3-frag; cols interleaved at 16 granule
    #pragma unroll
    for (int i = 0; i < 8; ++i) {
        int row = row0 + wm * 128 + i * 16 + ((lane >> 4) << 2);
        #pragma unroll
        for (int m = 0; m < 2; ++m) {
            int hc = ((col0 + wn * 64) >> 1) + m * 16 + (lane & 15);
            #pragma unroll
            for (int rg = 0; rg < 4; ++rg) {
                float a1 = acc[i][2 * m][rg];
                float a3 = acc[i][2 * m + 1][rg];
                float hv = (a1 / (1.f + __expf(-a1))) * a3;
                H[(size_t)(row + rg) * HIDN + hc] = f2bf(hv);
            }
        }
    }
}

// ------------- gemm2: 128x128, BK=64, 2-phase counted-vmcnt (r10) + XCD swizzle -------------
// 1D grid 1152 = 8 col x 144 row; same chunked-XCD map (q=144).
__global__ __launch_bounds__(256, 2)
void gemm2_2p(const uint16_t* __restrict__ Hg,
              const uint16_t* __restrict__ W2, uint16_t* __restrict__ H2,
              const int* __restrict__ offs) {
    constexpr int K = HIDN;       // 2048
    constexpr int NT = K / 64;    // 32 K-tiles
    __shared__ __align__(16) char lds[65536];

    int wg = ((blockIdx.x & 7) * 144) + (blockIdx.x >> 3);
    int row0 = (wg >> 3) * 128;
    int col0 = (wg & 7) * 128;

    int rsh = row0 - offs[NEXP];
    int e;
    if (rsh >= 0) {
        if (rsh >= 2 * T_TOK) return;
        e = NEXP + (rsh >> 12);
    } else {
        e = 0;
        while (row0 >= offs[e + 1]) ++e;
    }
    const uint16_t* wp = W2 + (size_t)e * DIMD * HIDN;

    int tid = threadIdx.x, lane = tid & 63, wid = tid >> 6;
    int wm = wid >> 1, wn = wid & 1;

    int chunk = (tid & 3) ^ ((tid >> 3) & 3);
    uint32_t aoff[2], boff[2];
    #pragma unroll
    for (int p = 0; p < 2; ++p) {
        int r = p * 64 + (tid >> 2);
        aoff[p] = (uint32_t)(row0 + r) * K + chunk * 8;
        boff[p] = (uint32_t)(col0 + r) * K + chunk * 8;
    }
    int ldsw = wid * 1024;

    int rslot = (((lane >> 4) ^ ((lane >> 1) & 3)) << 4);
    int aro = (wm * 64 + (lane & 15)) * 64 + rslot;            // + f*1024 + ks*8192
    int bro = (wn * 64 + (lane & 15)) * 64 + rslot + 16384;    // + f*1024 + ks*8192

    #define STG_A2(buf, kt, ks) { \
        gload16(Hg + aoff[0] + (kt) + (ks) * 32, (buf) + (ks) * 8192 + ldsw); \
        gload16(Hg + aoff[1] + (kt) + (ks) * 32, (buf) + (ks) * 8192 + 4096 + ldsw); }
    #define STG_B2(buf, kt, ks) { \
        gload16(wp + boff[0] + (kt) + (ks) * 32, (buf) + 16384 + (ks) * 8192 + ldsw); \
        gload16(wp + boff[1] + (kt) + (ks) * 32, (buf) + 16384 + (ks) * 8192 + 4096 + ldsw); }

    STG_A2(lds, 0, 0); STG_B2(lds, 0, 0);
    STG_A2(lds, 0, 1); STG_B2(lds, 0, 1);
    WAIT_VM4();
    BAR();

    f32x4 acc[4][4] = {};

    for (int t = 0; t < NT; ++t) {
        char* cur = lds + (t & 1) * 32768;
        char* nxt = lds + ((t + 1) & 1) * 32768;
        int kt1 = (t + 1) * 64;
        bool pre = (t + 1 < NT);
        s16x8 av[4], bv[4];

        // ---- ph1: ks0 (16 MFMA) ; stage ks0(t+1)
        #pragma unroll
        for (int f = 0; f < 4; ++f) av[f] = *(const s16x8*)(cur + aro + f * 1024);
        #pragma unroll
        for (int f = 0; f < 4; ++f) bv[f] = *(const s16x8*)(cur + bro + f * 1024);
        if (pre) { STG_A2(nxt, kt1, 0); STG_B2(nxt, kt1, 0); }
        BAR(); WAIT_LGKM0();
        __builtin_amdgcn_s_setprio(1);
        #pragma unroll
        for (int j = 0; j < 4; ++j)
            #pragma unroll
            for (int i = 0; i < 4; ++i)
                acc[i][j] = __builtin_amdgcn_mfma_f32_16x16x32_bf16(av[i], bv[j], acc[i][j], 0, 0, 0);
        __builtin_amdgcn_s_setprio(0);
        if (pre) { WAIT_VM4(); } else { WAIT_VM0(); }
        BAR();

        // ---- ph2: ks1 (16 MFMA) ; stage ks1(t+1)
        #pragma unroll
        for (int f = 0; f < 4; ++f) av[f] = *(const s16x8*)(cur + 8192 + aro + f * 1024);
        #pragma unroll
        for (int f = 0; f < 4; ++f) bv[f] = *(const s16x8*)(cur + 8192 + bro + f * 1024);
        if (pre) { STG_A2(nxt, kt1, 1); STG_B2(nxt, kt1, 1); }
        BAR(); WAIT_LGKM0();
        __builtin_amdgcn_s_setprio(1);
        #pragma unroll
        for (int j = 0; j < 4; ++j)
            #pragma unroll
            for (int i = 0; i < 4; ++i)
                acc[i][j] = __builtin_amdgcn_mfma_f32_16x16x32_bf16(av[i], bv[j], acc[i][j], 0, 0, 0);
        __builtin_amdgcn_s_setprio(0);
        if (pre) WAIT_VM4();
        BAR();
    }
    #undef STG_A2
    #undef STG_B2

    #pragma unroll
    for (int i = 0; i < 4; ++i) {
        #pragma unroll
        for (int j = 0; j < 4; ++j) {
            #pragma unroll
            for (int rg = 0; rg < 4; ++rg) {
                int row = row0 + wm * 64 + i * 16 + ((lane >> 4) << 2) + rg;
                int col = col0 + wn * 64 + j * 16 + (lane & 15);
                H2[(size_t)row * DIMD + col] = f2bf(acc[i][j][rg]);
            }
        }
    }
}

// ---------------- launch ----------------

extern "C" void kernel_launch(void* const* d_in, const int* in_sizes, int n_in,
                              void* d_out, int out_size, void* d_ws, size_t ws_size,
                              hipStream_t stream) {
    const float* x   = (const float*)d_in[0];
    const float* rw  = (const float*)d_in[1];
    const float* eb  = (const float*)d_in[2];
    const float* w1  = (const float*)d_in[3];
    const float* w3  = (const float*)d_in[4];
    const float* w2  = (const float*)d_in[5];
    const float* sw1 = (const float*)d_in[6];
    const float* sw3 = (const float*)d_in[7];
    const float* sw2 = (const float*)d_in[8];
    float* out = (float*)d_out;

    const size_t EW = (size_t)NEXP * HIDN * DIMD;
    const size_t SW = (size_t)2 * HIDN * DIMD;

    char* ws = (char*)d_ws;
    size_t off = 0;
    auto alloc = [&](size_t b) { char* p = ws + off; off = (off + b + 255) & ~(size_t)255; return p; };
    uint16_t* xb    = (uint16_t*)alloc((size_t)T_TOK * DIMD * 2);
    uint16_t* Hg    = (uint16_t*)alloc((size_t)RROWS * HIDN * 2);
    uint16_t* H2    = (uint16_t*)alloc((size_t)RROWS * DIMD * 2);
    uint16_t* w13   = (uint16_t*)alloc((size_t)10 * 4096 * 1024 * 2);  // interleaved, 10 experts
    uint16_t* w2all = (uint16_t*)alloc((EW + SW) * 2);
    int*   sel    = (int*)  alloc(T_TOK * 2 * 4);
    float* wgt    = (float*)alloc(T_TOK * 2 * 4);
    int*   row_of = (int*)  alloc(T_TOK * 2 * 4);
    int*   tok    = (int*)  alloc(RROWS * 4);
    int*   cntfill= (int*)  alloc(128);   // cnt = [0..15], fill = [16..31]
    int*   offs   = (int*)  alloc(64);
    int*   cnt  = cntfill;
    int*   fill = cntfill + 16;

    hipMemsetAsync(cntfill, 0, 128, stream);
    hipMemsetAsync(tok, 0, RROWS * 4, stream);   // pad rows -> token 0 (harmless)

    CvtArgs ca;
    ca.s[0] = w1;  ca.d[0] = w13;                           ca.nq[0] = (int)(EW / 4); ca.mode[0] = 1;
    ca.s[1] = sw1; ca.d[1] = w13 + (size_t)8 * 4096 * 1024; ca.nq[1] = (int)(SW / 4); ca.mode[1] = 1;
    ca.s[2] = w3;  ca.d[2] = w13;                           ca.nq[2] = (int)(EW / 4); ca.mode[2] = 2;
    ca.s[3] = sw3; ca.d[3] = w13 + (size_t)8 * 4096 * 1024; ca.nq[3] = (int)(SW / 4); ca.mode[3] = 2;
    ca.s[4] = w2;  ca.d[4] = w2all;                         ca.nq[4] = (int)(EW / 4); ca.mode[4] = 0;
    ca.s[5] = sw2; ca.d[5] = w2all + EW;                    ca.nq[5] = (int)(SW / 4); ca.mode[5] = 0;
    ca.s[6] = x;   ca.d[6] = xb;                            ca.nq[6] = T_TOK * DIMD / 4; ca.mode[6] = 0;
    cvt_all_kernel<<<2048, 256, 0, stream>>>(ca);

    router_kernel<<<128, 256, 0, stream>>>(x, rw, eb, sel, wgt, cnt);
    offs_kernel<<<1, 1, 0, stream>>>(cnt, offs);
    assign_kernel<<<64, 256, 0, stream>>>(sel, offs, fill, row_of, tok);

    gemm13_8p<<<1152, 512, 0, stream>>>(xb, tok, w13, Hg, offs);
    gemm2_2p<<<1152, 256, 0, stream>>>(Hg, w2all, H2, offs);

    combine_kernel<<<T_TOK, 128, 0, stream>>>(H2, row_of, wgt, offs, out);
}

// Round 13
// 477.422 us; speedup vs baseline: 1.0376x; 1.0107x over previous
//
#include <hip/hip_runtime.h>
#include <stdint.h>

#define T_TOK 4096
#define DIMD  1024
#define HIDN  2048
#define NEXP  8
#define RMAX  9216                  // routed: 8192 slots + 8*128 alignment pad
#define RROWS (RMAX + 2 * T_TOK)    // + 2 shared-expert segments = 17408 rows max

typedef float f32x4 __attribute__((ext_vector_type(4)));
typedef short s16x8 __attribute__((ext_vector_type(8)));

__device__ __forceinline__ uint16_t f2bf(float f) {
    uint32_t u = __builtin_bit_cast(uint32_t, f);
    u += 0x7fffu + ((u >> 16) & 1u);
    return (uint16_t)(u >> 16);
}
__device__ __forceinline__ float bf2f(uint32_t h) {
    return __builtin_bit_cast(float, h << 16);
}
__device__ __forceinline__ uint32_t pk2(float a, float b) {
    return (uint32_t)f2bf(a) | ((uint32_t)f2bf(b) << 16);
}
// swizzled LDS byte offset: 128B row pitch, XOR row bits into 16B-granule slot
__device__ __forceinline__ int swz(int r, int cbyte) {
    return r * 128 + (cbyte ^ ((r & 7) << 4));
}
// async global->LDS, 16B per lane, LDS dest = wave-uniform base + lane*16
__device__ __forceinline__ void gload16(const void* g, void* l) {
    __builtin_amdgcn_global_load_lds(
        (const __attribute__((address_space(1))) void*)g,
        (__attribute__((address_space(3))) void*)l, 16, 0, 0);
}
// Stage a 128x64 bf16 tile (16KB) into LDS with st-16 swizzle.
// LDS dest linear; global source inverse-swizzled so swz(r,cb) reads elem (r,cb).
__device__ __forceinline__ void stage128x64(const uint16_t* gbase, int ldk,
                                            char* lds, int wv, int lane) {
    #pragma unroll
    for (int i = 0; i < 4; ++i) {
        int s = (wv * 4 + i) * 64 + lane;
        int row = s >> 3;
        int cb = ((s & 7) << 4) ^ ((row & 7) << 4);
        gload16(gbase + (size_t)row * ldk + (cb >> 1), lds + ((wv * 4 + i) << 10));
    }
}

// ---------------- small kernels ----------------

struct CvtArgs {
    const float* s[7];
    uint16_t*    d[7];
    int          ng[7];   // number of 8-element groups
};

// straight f32 -> bf16 copy, 32B read / 16B write per lane per iter
__global__ void cvt_all_kernel(CvtArgs a) {
    int base = blockIdx.x * blockDim.x + threadIdx.x;
    int stride = gridDim.x * blockDim.x;
    #pragma unroll
    for (int seg = 0; seg < 7; ++seg) {
        const float4* sp = (const float4*)a.s[seg];
        uint4* dp = (uint4*)a.d[seg];
        int n = a.ng[seg];
        for (int i = base; i < n; i += stride) {
            float4 v0 = sp[2 * i];
            float4 v1 = sp[2 * i + 1];
            uint4 o;
            o.x = pk2(v0.x, v0.y); o.y = pk2(v0.z, v0.w);
            o.z = pk2(v1.x, v1.y); o.w = pk2(v1.z, v1.w);
            dp[i] = o;
        }
    }
}

// Router: 128 blocks x 256 thr; rw staged in LDS; 1 wave = 8 tokens.
__global__ __launch_bounds__(256)
void router_kernel(const float* __restrict__ x, const float* __restrict__ rw,
                   const float* __restrict__ bias,
                   int* __restrict__ sel, float* __restrict__ wgt,
                   int* __restrict__ cnt) {
    __shared__ float rws[NEXP * DIMD];
    int tid = threadIdx.x;
    for (int i = tid; i < NEXP * DIMD / 4; i += 256)
        ((float4*)rws)[i] = ((const float4*)rw)[i];
    __syncthreads();

    int wid = tid >> 6, lane = tid & 63;
    float b[NEXP];
    #pragma unroll
    for (int e = 0; e < NEXP; ++e) b[e] = bias[e];

    int t0 = (blockIdx.x * 4 + wid) * 8;
    for (int j = 0; j < 8; ++j) {
        int t = t0 + j;
        const float4* xr = (const float4*)(x + (size_t)t * DIMD);
        float p[NEXP] = {};
        #pragma unroll
        for (int c = 0; c < 4; ++c) {
            float4 xv = xr[c * 64 + lane];
            #pragma unroll
            for (int e = 0; e < NEXP; ++e) {
                float4 wv = *(const float4*)(rws + e * DIMD + c * 256 + lane * 4);
                p[e] += xv.x * wv.x + xv.y * wv.y + xv.z * wv.z + xv.w * wv.w;
            }
        }
        #pragma unroll
        for (int off = 32; off >= 1; off >>= 1) {
            #pragma unroll
            for (int e = 0; e < NEXP; ++e) p[e] += __shfl_xor(p[e], off, 64);
        }
        if (lane == 0) {
            #pragma unroll
            for (int e = 0; e < NEXP; ++e) p[e] += b[e];
            float l0 = -1e30f; int i0 = 0;
            #pragma unroll
            for (int e = 0; e < NEXP; ++e) { if (p[e] > l0) { l0 = p[e]; i0 = e; } }
            float l1 = -1e30f; int i1 = 0;
            #pragma unroll
            for (int e = 0; e < NEXP; ++e) { if (e == i0) continue; if (p[e] > l1) { l1 = p[e]; i1 = e; } }
            float e1 = expf(l1 - l0);      // l0 >= l1 -> e1 <= 1
            float d = 1.f + e1;
            sel[t * 2] = i0; sel[t * 2 + 1] = i1;
            wgt[t * 2] = 1.f / d; wgt[t * 2 + 1] = e1 / d;
            atomicAdd(&cnt[i0], 1);
            atomicAdd(&cnt[i1], 1);
        }
    }
}

__global__ void offs_kernel(const int* __restrict__ cnt, int* __restrict__ offs) {
    if (threadIdx.x == 0 && blockIdx.x == 0) {
        int o = 0;
        for (int e = 0; e < NEXP; ++e) { offs[e] = o; o += (cnt[e] + 127) & ~127; }
        offs[NEXP] = o;
    }
}

// slot -> row, row -> token (tok); also fills tok for the shared segments.
__global__ void assign_kernel(const int* __restrict__ sel, const int* __restrict__ offs,
                              int* __restrict__ fill, int* __restrict__ row_of,
                              int* __restrict__ tok) {
    int i = blockIdx.x * blockDim.x + threadIdx.x;
    if (i < 2 * T_TOK) {
        int e = sel[i];
        int r = offs[e] + atomicAdd(&fill[e], 1);
        row_of[i] = r;
        tok[r] = i >> 1;
    } else if (i < 4 * T_TOK) {
        int j = i - 2 * T_TOK;                       // 0..8191: shared rows
        tok[offs[NEXP] + j] = j & (T_TOK - 1);
    }
}

// out[t] = w0*H2[r0] + w1*H2[r1] + H2[s0] + H2[s1]  (pure write)
__global__ void combine_kernel(const uint16_t* __restrict__ H2, const int* __restrict__ row_of,
                               const float* __restrict__ wgt, const int* __restrict__ offs,
                               float* __restrict__ out) {
    int t = blockIdx.x;
    int c = threadIdx.x * 8;   // 128 threads * 8 cols
    int r0 = row_of[t * 2], r1 = row_of[t * 2 + 1];
    int s0 = offs[NEXP] + t, s1 = s0 + T_TOK;
    float w0 = wgt[t * 2], w1 = wgt[t * 2 + 1];
    uint4 a = *(const uint4*)(H2 + (size_t)r0 * DIMD + c);
    uint4 b = *(const uint4*)(H2 + (size_t)r1 * DIMD + c);
    uint4 u = *(const uint4*)(H2 + (size_t)s0 * DIMD + c);
    uint4 v = *(const uint4*)(H2 + (size_t)s1 * DIMD + c);
    float4 o0, o1;
    o0.x = w0 * bf2f(a.x & 0xffffu) + w1 * bf2f(b.x & 0xffffu) + bf2f(u.x & 0xffffu) + bf2f(v.x & 0xffffu);
    o0.y = w0 * bf2f(a.x >> 16)     + w1 * bf2f(b.x >> 16)     + bf2f(u.x >> 16)     + bf2f(v.x >> 16);
    o0.z = w0 * bf2f(a.y & 0xffffu) + w1 * bf2f(b.y & 0xffffu) + bf2f(u.y & 0xffffu) + bf2f(v.y & 0xffffu);
    o0.w = w0 * bf2f(a.y >> 16)     + w1 * bf2f(b.y >> 16)     + bf2f(u.y >> 16)     + bf2f(v.y >> 16);
    o1.x = w0 * bf2f(a.z & 0xffffu) + w1 * bf2f(b.z & 0xffffu) + bf2f(u.z & 0xffffu) + bf2f(v.z & 0xffffu);
    o1.y = w0 * bf2f(a.z >> 16)     + w1 * bf2f(b.z >> 16)     + bf2f(u.z >> 16)     + bf2f(v.z >> 16);
    o1.z = w0 * bf2f(a.w & 0xffffu) + w1 * bf2f(b.w & 0xffffu) + bf2f(u.w & 0xffffu) + bf2f(v.w & 0xffffu);
    o1.w = w0 * bf2f(a.w >> 16)     + w1 * bf2f(b.w >> 16)     + bf2f(u.w >> 16)     + bf2f(v.w >> 16);
    float* o = out + (size_t)t * DIMD + c;
    *(float4*)o = o0;
    *(float4*)(o + 4) = o1;
}

// ---------------- unified GEMM kernels (r6 structure — measured best) ----------------
// Row space: [0, offs[8]) routed (expert via offs), [offs[8], offs[8]+8192) shared
// (expert 8/9, 4096 rows each). A rows resolved through tok[] (gather fused into
// staging: global_load_lds source address is per-lane).
// Grid: x = col tile (fast, %8==0 -> weight panels pinned per XCD), y = row tile.

__global__ __launch_bounds__(256, 2)   // 2 blocks/CU: 128 acc regs, (256,3) spills
void gemm13_kernel(const uint16_t* __restrict__ xb, const int* __restrict__ tok,
                   const uint16_t* __restrict__ W1, const uint16_t* __restrict__ W3,
                   uint16_t* __restrict__ H, const int* __restrict__ offs) {
    __shared__ __align__(16) char lds[49152];
    char* As  = lds;
    char* B1s = lds + 16384;
    char* B3s = lds + 32768;

    const int K = DIMD;
    int row0 = blockIdx.y * 128;
    int rsh = row0 - offs[NEXP];
    int e;
    if (rsh >= 0) {
        if (rsh >= 2 * T_TOK) return;
        e = NEXP + (rsh >> 12);
    } else {
        e = 0;
        while (row0 >= offs[e + 1]) ++e;
    }
    const uint16_t* b1 = W1 + (size_t)e * HIDN * DIMD;
    const uint16_t* b3 = W3 + (size_t)e * HIDN * DIMD;
    int col0 = blockIdx.x * 128;

    int tid = threadIdx.x, lane = tid & 63;
    int wv = tid >> 6, wm = wv >> 1, wn = wv & 1;

    // per-lane A staging bases (token-indirected), fixed across K
    size_t abase[4];
    #pragma unroll
    for (int i = 0; i < 4; ++i) {
        int s = (wv * 4 + i) * 64 + lane;
        int row = s >> 3;
        int cb = ((s & 7) << 4) ^ ((row & 7) << 4);
        abase[i] = (size_t)tok[row0 + row] * DIMD + (cb >> 1);
    }

    f32x4 acc1[4][4] = {};
    f32x4 acc3[4][4] = {};

    for (int kt = 0; kt < K; kt += 64) {
        __syncthreads();
        #pragma unroll
        for (int i = 0; i < 4; ++i)
            gload16(xb + abase[i] + kt, As + ((wv * 4 + i) << 10));
        stage128x64(b1 + (size_t)col0 * K + kt, K, B1s, wv, lane);
        stage128x64(b3 + (size_t)col0 * K + kt, K, B3s, wv, lane);
        __syncthreads();   // compiler drains vmcnt before s_barrier

        #pragma unroll
        for (int s = 0; s < 2; ++s) {
            int cb = s * 64 + ((lane >> 4) << 4);
            s16x8 av[4];
            #pragma unroll
            for (int i = 0; i < 4; ++i)
                av[i] = *(const s16x8*)(As + swz(wm * 64 + i * 16 + (lane & 15), cb));
            #pragma unroll
            for (int j = 0; j < 4; ++j) {
                int br = wn * 64 + j * 16 + (lane & 15);
                s16x8 bv1 = *(const s16x8*)(B1s + swz(br, cb));
                s16x8 bv3 = *(const s16x8*)(B3s + swz(br, cb));
                #pragma unroll
                for (int i = 0; i < 4; ++i) {
                    acc1[i][j] = __builtin_amdgcn_mfma_f32_16x16x32_bf16(av[i], bv1, acc1[i][j], 0, 0, 0);
                    acc3[i][j] = __builtin_amdgcn_mfma_f32_16x16x32_bf16(av[i], bv3, acc3[i][j], 0, 0, 0);
                }
            }
        }
    }

    #pragma unroll
    for (int i = 0; i < 4; ++i) {
        #pragma unroll
        for (int j = 0; j < 4; ++j) {
            #pragma unroll
            for (int rg = 0; rg < 4; ++rg) {
                int row = row0 + wm * 64 + i * 16 + ((lane >> 4) << 2) + rg;
                int col = col0 + wn * 64 + j * 16 + (lane & 15);
                float a1 = acc1[i][j][rg];
                float a3 = acc3[i][j][rg];
                float hv = (a1 / (1.f + __expf(-a1))) * a3;   // silu(a1)*a3
                H[(size_t)row * HIDN + col] = f2bf(hv);
            }
        }
    }
}

// GEMM2: H2[r, 0..1024) = Hg[r, :] @ w2[e]^T, bf16 out, same row space as gemm13.
__global__ __launch_bounds__(256, 3)
void gemm2_kernel(const uint16_t* __restrict__ Hg,
                  const uint16_t* __restrict__ W2, uint16_t* __restrict__ H2,
                  const int* __restrict__ offs) {
    __shared__ __align__(16) char lds[32768];
    char* As = lds;
    char* Bs = lds + 16384;

    const int K = HIDN;
    int row0 = blockIdx.y * 128;
    int rsh = row0 - offs[NEXP];
    int e;
    if (rsh >= 0) {
        if (rsh >= 2 * T_TOK) return;
        e = NEXP + (rsh >> 12);
    } else {
        e = 0;
        while (row0 >= offs[e + 1]) ++e;
    }
    const uint16_t* b2 = W2 + (size_t)e * DIMD * HIDN;
    int col0 = blockIdx.x * 128;

    int tid = threadIdx.x, lane = tid & 63;
    int wv = tid >> 6, wm = wv >> 1, wn = wv & 1;

    f32x4 acc[4][4] = {};

    for (int kt = 0; kt < K; kt += 64) {
        __syncthreads();
        stage128x64(Hg + (size_t)row0 * K + kt, K, As, wv, lane);
        stage128x64(b2 + (size_t)col0 * K + kt, K, Bs, wv, lane);
        __syncthreads();

        #pragma unroll
        for (int s = 0; s < 2; ++s) {
            int cb = s * 64 + ((lane >> 4) << 4);
            s16x8 av[4];
            #pragma unroll
            for (int i = 0; i < 4; ++i)
                av[i] = *(const s16x8*)(As + swz(wm * 64 + i * 16 + (lane & 15), cb));
            #pragma unroll
            for (int j = 0; j < 4; ++j) {
                s16x8 bv = *(const s16x8*)(Bs + swz(wn * 64 + j * 16 + (lane & 15), cb));
                #pragma unroll
                for (int i = 0; i < 4; ++i)
                    acc[i][j] = __builtin_amdgcn_mfma_f32_16x16x32_bf16(av[i], bv, acc[i][j], 0, 0, 0);
            }
        }
    }

    #pragma unroll
    for (int i = 0; i < 4; ++i) {
        #pragma unroll
        for (int j = 0; j < 4; ++j) {
            #pragma unroll
            for (int rg = 0; rg < 4; ++rg) {
                int row = row0 + wm * 64 + i * 16 + ((lane >> 4) << 2) + rg;
                int col = col0 + wn * 64 + j * 16 + (lane & 15);
                H2[(size_t)row * DIMD + col] = f2bf(acc[i][j][rg]);
            }
        }
    }
}

// ---------------- launch ----------------

extern "C" void kernel_launch(void* const* d_in, const int* in_sizes, int n_in,
                              void* d_out, int out_size, void* d_ws, size_t ws_size,
                              hipStream_t stream) {
    const float* x   = (const float*)d_in[0];
    const float* rw  = (const float*)d_in[1];
    const float* eb  = (const float*)d_in[2];
    const float* w1  = (const float*)d_in[3];
    const float* w3  = (const float*)d_in[4];
    const float* w2  = (const float*)d_in[5];
    const float* sw1 = (const float*)d_in[6];
    const float* sw3 = (const float*)d_in[7];
    const float* sw2 = (const float*)d_in[8];
    float* out = (float*)d_out;

    const size_t EW = (size_t)NEXP * HIDN * DIMD;   // elements in 8 routed expert weights
    const size_t SW = (size_t)2 * HIDN * DIMD;      // elements in 2 shared expert weights

    char* ws = (char*)d_ws;
    size_t off = 0;
    auto alloc = [&](size_t b) { char* p = ws + off; off = (off + b + 255) & ~(size_t)255; return p; };
    uint16_t* xb    = (uint16_t*)alloc((size_t)T_TOK * DIMD * 2);    // x in bf16
    uint16_t* Hg    = (uint16_t*)alloc((size_t)RROWS * HIDN * 2);    // hidden, unified rows
    uint16_t* H2    = (uint16_t*)alloc((size_t)RROWS * DIMD * 2);    // FFN outputs, unified rows
    uint16_t* w1all = (uint16_t*)alloc((EW + SW) * 2);               // 10 experts
    uint16_t* w3all = (uint16_t*)alloc((EW + SW) * 2);
    uint16_t* w2all = (uint16_t*)alloc((EW + SW) * 2);
    int*   sel    = (int*)  alloc(T_TOK * 2 * 4);
    float* wgt    = (float*)alloc(T_TOK * 2 * 4);
    int*   row_of = (int*)  alloc(T_TOK * 2 * 4);
    int*   tok    = (int*)  alloc(RROWS * 4);
    int*   cntfill= (int*)  alloc(128);   // cnt = [0..15], fill = [16..31]
    int*   offs   = (int*)  alloc(64);
    int*   cnt  = cntfill;
    int*   fill = cntfill + 16;

    hipMemsetAsync(cntfill, 0, 128, stream);
    hipMemsetAsync(tok, 0, RROWS * 4, stream);   // pad rows -> token 0 (harmless)

    // all f32 -> bf16 conversions in one HBM-bound pass; shared experts appended
    // as experts 8..9 of the unified weight buffers. 8-element groups.
    CvtArgs ca;
    ca.s[0] = w1;  ca.d[0] = w1all;      ca.ng[0] = (int)(EW / 8);
    ca.s[1] = sw1; ca.d[1] = w1all + EW; ca.ng[1] = (int)(SW / 8);
    ca.s[2] = w3;  ca.d[2] = w3all;      ca.ng[2] = (int)(EW / 8);
    ca.s[3] = sw3; ca.d[3] = w3all + EW; ca.ng[3] = (int)(SW / 8);
    ca.s[4] = w2;  ca.d[4] = w2all;      ca.ng[4] = (int)(EW / 8);
    ca.s[5] = sw2; ca.d[5] = w2all + EW; ca.ng[5] = (int)(SW / 8);
    ca.s[6] = x;   ca.d[6] = xb;         ca.ng[6] = T_TOK * DIMD / 8;
    cvt_all_kernel<<<2048, 256, 0, stream>>>(ca);

    router_kernel<<<128, 256, 0, stream>>>(x, rw, eb, sel, wgt, cnt);
    offs_kernel<<<1, 1, 0, stream>>>(cnt, offs);
    assign_kernel<<<64, 256, 0, stream>>>(sel, offs, fill, row_of, tok);

    // unified expert FFN over all rows (routed segments + 2 shared segments)
    gemm13_kernel<<<dim3(HIDN / 128, RROWS / 128), 256, 0, stream>>>(xb, tok, w1all, w3all, Hg, offs);
    gemm2_kernel<<<dim3(DIMD / 128, RROWS / 128), 256, 0, stream>>>(Hg, w2all, H2, offs);

    combine_kernel<<<T_TOK, 128, 0, stream>>>(H2, row_of, wgt, offs, out);
}